// Round 1
// baseline (445.836 us; speedup 1.0000x reference)
//
#include <hip/hip_runtime.h>

// Pass 1: avg-pool 3x3 stride2 pad1 (count_include_pad -> always /9).
// pooled layout: [B*C][128][128], B*C = 1024.
__global__ __launch_bounds__(256) void pool_k(const float* __restrict__ f,
                                              float* __restrict__ pooled) {
    int idx = blockIdx.x * 256 + threadIdx.x;   // over 16*64*128*128
    int px = idx & 127;
    int py = (idx >> 7) & 127;
    int bc = idx >> 14;                          // 0..1023
    const float* fp = f + (size_t)bc * 65536;
    int y0 = 2 * py - 1, x0 = 2 * px - 1;
    float s = 0.f;
#pragma unroll
    for (int ky = 0; ky < 3; ++ky) {
        int y = y0 + ky;
        if ((unsigned)y < 256u) {
            const float* row = fp + y * 256;
#pragma unroll
            for (int kx = 0; kx < 3; ++kx) {
                int x = x0 + kx;
                if ((unsigned)x < 256u) s += row[x];
            }
        }
    }
    pooled[idx] = s * (1.0f / 9.0f);
}

// Pass 2: each thread owns one 2x2 output quad (shared py,px).
// For each channel: load 2x float2 feature + 9 pooled neighbors,
// accumulate (f - p)^2 into acc[quad][neighbor]; output = max over 8 neighbors.
__global__ __launch_bounds__(256) void diff_k(const float* __restrict__ f,
                                              const float* __restrict__ pooled,
                                              float* __restrict__ out,
                                              const int* __restrict__ distp) {
    int dist = *distp;
    int idx = blockIdx.x * 256 + threadIdx.x;    // over 16*128*128
    int tx = idx & 127;
    int ty = (idx >> 7) & 127;
    int b  = idx >> 14;

    int pyv[3], pxv[3];
#pragma unroll
    for (int k = 0; k < 3; ++k) {
        int t = ty + (k - 1) * dist;
        t %= 128; if (t < 0) t += 128;
        pyv[k] = t;
        t = tx + (k - 1) * dist;
        t %= 128; if (t < 0) t += 128;
        pxv[k] = t;
    }

    const float* fb = f + (size_t)b * 64 * 65536;
    const float* pb = pooled + (size_t)b * 64 * 16384;
    int foff = (2 * ty) * 256 + 2 * tx;

    float acc[4][8];
#pragma unroll
    for (int q = 0; q < 4; ++q)
#pragma unroll
        for (int n = 0; n < 8; ++n) acc[q][n] = 0.f;

    for (int c = 0; c < 64; ++c) {
        const float* fp = fb + (size_t)c * 65536 + foff;
        float2 r0 = *(const float2*)(fp);
        float2 r1 = *(const float2*)(fp + 256);
        float fv[4] = { r0.x, r0.y, r1.x, r1.y };
        const float* pp = pb + (size_t)c * 16384;
        float p[9];
#pragma unroll
        for (int k = 0; k < 3; ++k) {
            const float* prow = pp + pyv[k] * 128;
#pragma unroll
            for (int j = 0; j < 3; ++j) p[k * 3 + j] = prow[pxv[j]];
        }
#pragma unroll
        for (int q = 0; q < 4; ++q) {
            float fq = fv[q];
            int n = 0;
#pragma unroll
            for (int k = 0; k < 9; ++k) {
                if (k == 4) continue;           // center = unshifted, not used
                float dv = fq - p[k];
                acc[q][n] = fmaf(dv, dv, acc[q][n]);
                ++n;
            }
        }
    }

    float* ob = out + (size_t)b * 65536;
#pragma unroll
    for (int q = 0; q < 4; ++q) {
        float m = acc[q][0];
#pragma unroll
        for (int n = 1; n < 8; ++n) m = fmaxf(m, acc[q][n]);
        int yy = 2 * ty + (q >> 1);
        int xx = 2 * tx + (q & 1);
        ob[yy * 256 + xx] = m;
    }
}

extern "C" void kernel_launch(void* const* d_in, const int* in_sizes, int n_in,
                              void* d_out, int out_size, void* d_ws, size_t ws_size,
                              hipStream_t stream) {
    const float* feature = (const float*)d_in[0];
    const int*   distp   = (const int*)d_in[1];
    float* out    = (float*)d_out;
    float* pooled = (float*)d_ws;   // 16*64*128*128 f32 = 64 MiB

    // Pass 1: 16*64*128*128 = 16,777,216 threads
    pool_k<<<65536, 256, 0, stream>>>(feature, pooled);
    // Pass 2: 16*128*128 = 262,144 threads (one per 2x2 output quad)
    diff_k<<<1024, 256, 0, stream>>>(feature, pooled, out, distp);
}

// Round 2
// 427.409 us; speedup vs baseline: 1.0431x; 1.0431x over previous
//
#include <hip/hip_runtime.h>

// Pass 1: avg-pool 3x3 stride2 pad1 (count_include_pad -> /9 always).
// Each thread computes 4 consecutive pooled outputs px=4j..4j+3.
// Per row needs input cols 8j-1 .. 8j+7: one scalar + two aligned float4.
// pooled layout: [B*C][128][128], B*C = 1024.
__global__ __launch_bounds__(256) void pool_k(const float* __restrict__ f,
                                              float* __restrict__ pooled) {
    int idx = blockIdx.x * 256 + threadIdx.x;   // over 1024*128*32
    int j  = idx & 31;                          // x-group (4 outputs)
    int py = (idx >> 5) & 127;
    int bc = idx >> 12;                         // 0..1023
    const float* fp = f + (size_t)bc * 65536;
    int y0 = 2 * py - 1;
    float s0 = 0.f, s1 = 0.f, s2 = 0.f, s3 = 0.f;
#pragma unroll
    for (int ky = 0; ky < 3; ++ky) {
        int y = y0 + ky;
        if ((unsigned)y < 256u) {
            const float* row = fp + y * 256 + 8 * j;
            float  e  = (j > 0) ? row[-1] : 0.f;         // col 8j-1 (zero-pad)
            float4 v0 = *(const float4*)(row);            // cols 8j..8j+3
            float4 v1 = *(const float4*)(row + 4);        // cols 8j+4..8j+7
            s0 += e    + v0.x + v0.y;
            s1 += v0.y + v0.z + v0.w;
            s2 += v0.w + v1.x + v1.y;
            s3 += v1.y + v1.z + v1.w;
        }
    }
    const float inv9 = 1.0f / 9.0f;
    float4 o = make_float4(s0 * inv9, s1 * inv9, s2 * inv9, s3 * inv9);
    *(float4*)(pooled + (size_t)bc * 16384 + py * 128 + 4 * j) = o;
}

// Pass 2: one thread per 2x2 output quad.
// Sum_c (f - p_n)^2 = Sum f^2 - 2*Sum f*p_n + Sum p_n^2
//   sf2[q]   : per-pixel  (4 fma/ch)
//   sp2[n]   : per-neighbor, shared by the 4 quad pixels (8 fma/ch)
//   dot[q][n]: 32 fma/ch
// Center pooled value is never used -> 8 pooled loads/ch.
__global__ __launch_bounds__(256) void diff_k(const float* __restrict__ f,
                                              const float* __restrict__ pooled,
                                              float* __restrict__ out,
                                              const int* __restrict__ distp) {
    int dist = *distp;
    int idx = blockIdx.x * 256 + threadIdx.x;    // over 16*128*128
    int tx = idx & 127;
    int ty = (idx >> 7) & 127;
    int b  = idx >> 14;

    int pyv[3], pxv[3];
#pragma unroll
    for (int k = 0; k < 3; ++k) {
        int t = ty + (k - 1) * dist;
        t %= 128; if (t < 0) t += 128;
        pyv[k] = t;
        t = tx + (k - 1) * dist;
        t %= 128; if (t < 0) t += 128;
        pxv[k] = t;
    }

    const float* fb = f + (size_t)b * 64 * 65536;
    const float* pb = pooled + (size_t)b * 64 * 16384;
    int foff = (2 * ty) * 256 + 2 * tx;

    float dot[4][8], sp2[8], sf2[4];
#pragma unroll
    for (int q = 0; q < 4; ++q) { sf2[q] = 0.f;
#pragma unroll
        for (int n = 0; n < 8; ++n) dot[q][n] = 0.f; }
#pragma unroll
    for (int n = 0; n < 8; ++n) sp2[n] = 0.f;

    for (int c = 0; c < 64; ++c) {
        const float* fp = fb + (size_t)c * 65536 + foff;
        float2 r0 = *(const float2*)(fp);
        float2 r1 = *(const float2*)(fp + 256);
        float fv[4] = { r0.x, r0.y, r1.x, r1.y };

        const float* pp  = pb + (size_t)c * 16384;
        const float* pr0 = pp + pyv[0] * 128;
        const float* pr1 = pp + pyv[1] * 128;
        const float* pr2 = pp + pyv[2] * 128;
        float p[8];
        p[0] = pr0[pxv[0]]; p[1] = pr0[pxv[1]]; p[2] = pr0[pxv[2]];
        p[3] = pr1[pxv[0]];                     p[4] = pr1[pxv[2]];
        p[5] = pr2[pxv[0]]; p[6] = pr2[pxv[1]]; p[7] = pr2[pxv[2]];

#pragma unroll
        for (int n = 0; n < 8; ++n) sp2[n] = fmaf(p[n], p[n], sp2[n]);
#pragma unroll
        for (int q = 0; q < 4; ++q) {
            float fq = fv[q];
            sf2[q] = fmaf(fq, fq, sf2[q]);
#pragma unroll
            for (int n = 0; n < 8; ++n) dot[q][n] = fmaf(fq, p[n], dot[q][n]);
        }
    }

    float* ob = out + (size_t)b * 65536;
#pragma unroll
    for (int q = 0; q < 4; ++q) {
        float m = -3.4e38f;
#pragma unroll
        for (int n = 0; n < 8; ++n) {
            float v = fmaf(-2.f, dot[q][n], sf2[q] + sp2[n]);
            m = fmaxf(m, v);
        }
        int yy = 2 * ty + (q >> 1);
        int xx = 2 * tx + (q & 1);
        ob[yy * 256 + xx] = m;
    }
}

extern "C" void kernel_launch(void* const* d_in, const int* in_sizes, int n_in,
                              void* d_out, int out_size, void* d_ws, size_t ws_size,
                              hipStream_t stream) {
    const float* feature = (const float*)d_in[0];
    const int*   distp   = (const int*)d_in[1];
    float* out    = (float*)d_out;
    float* pooled = (float*)d_ws;   // 16*64*128*128 f32 = 64 MiB

    // Pass 1: 1024*128*32 = 4,194,304 threads (4 pooled outputs each)
    pool_k<<<16384, 256, 0, stream>>>(feature, pooled);
    // Pass 2: 16*128*128 = 262,144 threads (one 2x2 output quad each)
    diff_k<<<1024, 256, 0, stream>>>(feature, pooled, out, distp);
}

// Round 5
// 416.525 us; speedup vs baseline: 1.0704x; 1.0261x over previous
//
#include <hip/hip_runtime.h>

// Fused avg-pool(3x3,s2,p1,/9) + 8-neighbor rolled squared-distance + channel-sum + max.
// One block = (batch, band of QR=4 pooled rows). 512 threads, 1 thread per 2x2 quad.
// Per channel: cooperatively pool PR = QR+2*dist rows into a SINGLE LDS buffer,
// __syncthreads, accumulate   sum_c (f-p_n)^2 = sf2 + sp2[n] - 2*dot[n],
// __syncthreads (protects next channel's overwrite). No double buffering,
// no read-before-write (LDS additionally zeroed at start so every launch is
// bit-identical in its LDS initial state).

#define QR 4            // pooled (quad) rows per block
#define MAXPR (QR + 10) // supports dist <= 5

__global__ __launch_bounds__(512) void fused_k(const float* __restrict__ f,
                                               float* __restrict__ out,
                                               const int* __restrict__ distp) {
    __shared__ __align__(16) float ps[MAXPR][128];
    const int dist = *distp;
    const int PR   = QR + 2 * dist;          // pooled rows needed by this band

    const int band = blockIdx.x & 31;        // 32 bands of QR=4 pooled rows
    const int b    = blockIdx.x >> 5;        // batch
    const int ty0  = band * QR;
    const int tid  = threadIdx.x;
    const int qr   = tid >> 7;               // 0..3 quad row within band
    const int tx   = tid & 127;              // quad col
    const int ty   = ty0 + qr;

    // launch-invariant LDS initial state
    for (int w = tid; w < MAXPR * 128; w += 512) ((float*)ps)[w] = 0.f;
    __syncthreads();

    const float* fb = f + (size_t)b * 64 * 65536;
    const int foff = (2 * ty) * 256 + 2 * tx;

    const int cxm = (tx - dist) & 127;
    const int cxp = (tx + dist) & 127;
    const int rm  = qr;                      // LDS row of neighbor dy=-dist
    const int rc  = qr + dist;               // dy=0
    const int rp  = qr + 2 * dist;           // dy=+dist

    float dot[4][8], sp2[8], sf2[4];
#pragma unroll
    for (int q = 0; q < 4; ++q) { sf2[q] = 0.f;
#pragma unroll
        for (int n = 0; n < 8; ++n) dot[q][n] = 0.f; }
#pragma unroll
    for (int n = 0; n < 8; ++n) sp2[n] = 0.f;

    for (int c = 0; c < 64; ++c) {
        const float* fc = fb + (size_t)c * 65536;

        // ---- phase 1: pool PR rows into LDS (each workitem: 2 pooled cols) ----
        for (int w = tid; w < PR * 64; w += 512) {
            int r = w >> 6;                  // LDS row 0..PR-1
            int j = w & 63;                  // pooled cols 2j, 2j+1
            int pr = (ty0 - dist + r) & 127; // absolute pooled row (roll wrap)
            float s0 = 0.f, s1 = 0.f;
            int y0 = 2 * pr - 1;
#pragma unroll
            for (int ky = 0; ky < 3; ++ky) {
                int y = y0 + ky;
                if ((unsigned)y < 256u) {    // zero-pad at image boundary
                    const float* row = fc + y * 256 + 4 * j;
                    float  e = (j > 0) ? row[-1] : 0.f;
                    float4 v = *(const float4*)row;
                    s0 += e   + v.x + v.y;
                    s1 += v.y + v.z + v.w;
                }
            }
            *(float2*)&ps[r][2 * j] =
                make_float2(s0 * (1.f / 9.f), s1 * (1.f / 9.f));
        }
        __syncthreads();                     // writes visible before reads

        // ---- phase 2: accumulate this channel ----
        const float* fp = fc + foff;
        float2 q0 = *(const float2*)(fp);
        float2 q1 = *(const float2*)(fp + 256);
        float fv[4] = { q0.x, q0.y, q1.x, q1.y };

        float p[8];
        p[0] = ps[rm][cxm]; p[1] = ps[rm][tx]; p[2] = ps[rm][cxp];
        p[3] = ps[rc][cxm];                    p[4] = ps[rc][cxp];
        p[5] = ps[rp][cxm]; p[6] = ps[rp][tx]; p[7] = ps[rp][cxp];

#pragma unroll
        for (int n = 0; n < 8; ++n) sp2[n] = fmaf(p[n], p[n], sp2[n]);
#pragma unroll
        for (int q = 0; q < 4; ++q) {
            float fq = fv[q];
            sf2[q] = fmaf(fq, fq, sf2[q]);
#pragma unroll
            for (int n = 0; n < 8; ++n) dot[q][n] = fmaf(fq, p[n], dot[q][n]);
        }
        __syncthreads();                     // reads done before next overwrite
    }

    // ---- epilogue: max over 8 neighbors, write 2x2 quad ----
    float res[4];
#pragma unroll
    for (int q = 0; q < 4; ++q) {
        float m = -3.4e38f;
#pragma unroll
        for (int n = 0; n < 8; ++n)
            m = fmaxf(m, fmaf(-2.f, dot[q][n], sf2[q] + sp2[n]));
        res[q] = m;
    }
    float* op = out + (size_t)b * 65536 + foff;
    *(float2*)(op)       = make_float2(res[0], res[1]);
    *(float2*)(op + 256) = make_float2(res[2], res[3]);
}

extern "C" void kernel_launch(void* const* d_in, const int* in_sizes, int n_in,
                              void* d_out, int out_size, void* d_ws, size_t ws_size,
                              hipStream_t stream) {
    const float* feature = (const float*)d_in[0];
    const int*   distp   = (const int*)d_in[1];
    float* out = (float*)d_out;

    // 16 batches x 32 bands = 512 blocks, 512 threads each
    fused_k<<<512, 512, 0, stream>>>(feature, out, distp);
}

// Round 6
// 377.779 us; speedup vs baseline: 1.1801x; 1.1026x over previous
//
#include <hip/hip_runtime.h>

// Fused avg-pool(3x3,s2,p1,/9) + 8-neighbor rolled squared-distance + channel-sum + max,
// 1-deep software-pipelined: channel c+1's global loads (pool inputs + feature quad)
// are issued before channel c's values are consumed, hiding HBM/L2 latency across a
// full channel iteration. Single LDS buffer, two barriers per channel (sync -> write
// -> sync -> read). One block = (batch, band of QR=4 pooled rows), 512 threads,
// 1 thread per 2x2 output quad.

#define QR 4            // pooled (quad) rows per block
#define MAXPR (QR + 10) // supports dist <= 5

__global__ __launch_bounds__(512, 4) void fused_k(const float* __restrict__ f,
                                                  float* __restrict__ out,
                                                  const int* __restrict__ distp) {
    __shared__ __align__(16) float ps[MAXPR][128];
    const int dist = *distp;
    const int PR   = QR + 2 * dist;          // pooled rows needed by this band

    const int band = blockIdx.x & 31;        // 32 bands of QR=4 pooled rows
    const int b    = blockIdx.x >> 5;        // batch
    const int ty0  = band * QR;
    const int tid  = threadIdx.x;
    const int qr   = tid >> 7;               // 0..3 quad row within band
    const int tx   = tid & 127;              // quad col
    const int ty   = ty0 + qr;

    // launch-invariant LDS initial state
    for (int w = tid; w < MAXPR * 128; w += 512) ((float*)ps)[w] = 0.f;
    __syncthreads();

    const float* fb = f + (size_t)b * 64 * 65536;
    const int foff = (2 * ty) * 256 + 2 * tx;

    const int cxm = (tx - dist) & 127;
    const int cxp = (tx + dist) & 127;
    const int rm  = qr;                      // LDS row of neighbor dy=-dist
    const int rc  = qr + dist;               // dy=0
    const int rp  = qr + 2 * dist;           // dy=+dist

    // this thread's pool work item (exactly one when PR*64 <= 512, i.e. dist <= 2)
    const bool havew = tid < PR * 64;
    const int  r   = tid >> 6;               // LDS row 0..PR-1
    const int  j   = tid & 63;               // pooled cols 2j, 2j+1
    const int  prr = (ty0 - dist + r) & 127; // absolute pooled row (roll wrap)
    const int  y0  = 2 * prr - 1;

    float dot[4][8], sp2[8], sf2[4];
#pragma unroll
    for (int q = 0; q < 4; ++q) { sf2[q] = 0.f;
#pragma unroll
        for (int n = 0; n < 8; ++n) dot[q][n] = 0.f; }
#pragma unroll
    for (int n = 0; n < 8; ++n) sp2[n] = 0.f;

    // ---- prologue: prefetch channel 0 ----
    float4 pv0, pv1, pv2; float pe0, pe1, pe2;
    float2 fqa, fqb;
    {
        const float* fc = fb;
        pv0 = pv1 = pv2 = make_float4(0.f, 0.f, 0.f, 0.f);
        pe0 = pe1 = pe2 = 0.f;
#pragma unroll
        for (int ky = 0; ky < 3; ++ky) {
            int y = y0 + ky;
            if (havew && (unsigned)y < 256u) {
                const float* row = fc + y * 256 + 4 * j;
                float  e = (j > 0) ? row[-1] : 0.f;
                float4 v = *(const float4*)row;
                if (ky == 0) { pv0 = v; pe0 = e; }
                else if (ky == 1) { pv1 = v; pe1 = e; }
                else { pv2 = v; pe2 = e; }
            }
        }
        fqa = *(const float2*)(fc + foff);
        fqb = *(const float2*)(fc + foff + 256);
    }

    for (int c = 0; c < 64; ++c) {
        // ---- issue channel c+1 loads (consumed next iteration) ----
        const int cn = (c + 1 < 64) ? c + 1 : 63;
        const float* fcn = fb + (size_t)cn * 65536;
        float4 nv0, nv1, nv2; float ne0, ne1, ne2;
        nv0 = nv1 = nv2 = make_float4(0.f, 0.f, 0.f, 0.f);
        ne0 = ne1 = ne2 = 0.f;
#pragma unroll
        for (int ky = 0; ky < 3; ++ky) {
            int y = y0 + ky;
            if (havew && (unsigned)y < 256u) {
                const float* row = fcn + y * 256 + 4 * j;
                float  e = (j > 0) ? row[-1] : 0.f;
                float4 v = *(const float4*)row;
                if (ky == 0) { nv0 = v; ne0 = e; }
                else if (ky == 1) { nv1 = v; ne1 = e; }
                else { nv2 = v; ne2 = e; }
            }
        }
        float2 nfa = *(const float2*)(fcn + foff);
        float2 nfb = *(const float2*)(fcn + foff + 256);

        // ---- pool channel c from prefetched regs ----
        float s0 = (pe0 + pv0.x + pv0.y) + (pe1 + pv1.x + pv1.y) + (pe2 + pv2.x + pv2.y);
        float s1 = (pv0.y + pv0.z + pv0.w) + (pv1.y + pv1.z + pv1.w) + (pv2.y + pv2.z + pv2.w);

        __syncthreads();                     // prev channel's LDS reads complete
        if (havew)
            *(float2*)&ps[r][2 * j] = make_float2(s0 * (1.f / 9.f), s1 * (1.f / 9.f));
        // fallback for dist > 2 (PR*64 > 512): non-pipelined extra work items
        for (int w = tid + 512; w < PR * 64; w += 512) {
            int rr = w >> 6, jj = w & 63;
            int pr2 = (ty0 - dist + rr) & 127;
            float t0 = 0.f, t1 = 0.f;
            int yy0 = 2 * pr2 - 1;
#pragma unroll
            for (int ky = 0; ky < 3; ++ky) {
                int y = yy0 + ky;
                if ((unsigned)y < 256u) {
                    const float* row = fb + (size_t)c * 65536 + y * 256 + 4 * jj;
                    float  e = (jj > 0) ? row[-1] : 0.f;
                    float4 v = *(const float4*)row;
                    t0 += e   + v.x + v.y;
                    t1 += v.y + v.z + v.w;
                }
            }
            *(float2*)&ps[rr][2 * jj] = make_float2(t0 * (1.f / 9.f), t1 * (1.f / 9.f));
        }
        __syncthreads();                     // writes visible

        // ---- phase 2: accumulate channel c ----
        float fv[4] = { fqa.x, fqa.y, fqb.x, fqb.y };
        float p[8];
        p[0] = ps[rm][cxm]; p[1] = ps[rm][tx]; p[2] = ps[rm][cxp];
        p[3] = ps[rc][cxm];                    p[4] = ps[rc][cxp];
        p[5] = ps[rp][cxm]; p[6] = ps[rp][tx]; p[7] = ps[rp][cxp];

#pragma unroll
        for (int n = 0; n < 8; ++n) sp2[n] = fmaf(p[n], p[n], sp2[n]);
#pragma unroll
        for (int q = 0; q < 4; ++q) {
            float fq = fv[q];
            sf2[q] = fmaf(fq, fq, sf2[q]);
#pragma unroll
            for (int n = 0; n < 8; ++n) dot[q][n] = fmaf(fq, p[n], dot[q][n]);
        }

        // ---- rotate prefetch registers ----
        pv0 = nv0; pv1 = nv1; pv2 = nv2;
        pe0 = ne0; pe1 = ne1; pe2 = ne2;
        fqa = nfa; fqb = nfb;
    }

    // ---- epilogue: max over 8 neighbors, write 2x2 quad ----
    float res[4];
#pragma unroll
    for (int q = 0; q < 4; ++q) {
        float m = -3.4e38f;
#pragma unroll
        for (int n = 0; n < 8; ++n)
            m = fmaxf(m, fmaf(-2.f, dot[q][n], sf2[q] + sp2[n]));
        res[q] = m;
    }
    float* op = out + (size_t)b * 65536 + foff;
    *(float2*)(op)       = make_float2(res[0], res[1]);
    *(float2*)(op + 256) = make_float2(res[2], res[3]);
}

extern "C" void kernel_launch(void* const* d_in, const int* in_sizes, int n_in,
                              void* d_out, int out_size, void* d_ws, size_t ws_size,
                              hipStream_t stream) {
    const float* feature = (const float*)d_in[0];
    const int*   distp   = (const int*)d_in[1];
    float* out = (float*)d_out;

    // 16 batches x 32 bands = 512 blocks, 512 threads each
    fused_k<<<512, 512, 0, stream>>>(feature, out, distp);
}